// Round 9
// baseline (233.150 us; speedup 1.0000x reference)
//
#include <hip/hip_runtime.h>
#include <hip/hip_bf16.h>

#define BB 2
#define SS 513
#define HH 512
#define NHH 8
#define DDIM 64

typedef float f32x4v __attribute__((ext_vector_type(4)));
typedef int i32x4v __attribute__((ext_vector_type(4)));

__device__ __forceinline__ float dot4(float4 a, float4 b) {
  return a.x * b.x + a.y * b.y + a.z * b.z + a.w * b.w;
}
__device__ __forceinline__ float4 add4(float4 a, float4 b) {
  return make_float4(a.x + b.x, a.y + b.y, a.z + b.z, a.w + b.w);
}

__device__ __forceinline__ bool graph_at(const void* g, int isBool, size_t idx) {
  if (isBool) return ((const unsigned char*)g)[idx] != 0;
  return ((const int*)g)[idx] != 0;
}

// ---- bf16 helpers (RNE) -----------------------------------------------------
__device__ __forceinline__ unsigned int f2bf(float f) {
  unsigned int u = __float_as_uint(f);
  return (u + 0x7FFFu + ((u >> 16) & 1u)) >> 16;
}
__device__ __forceinline__ float bf2f(unsigned int h) {
  return __uint_as_float(h << 16);
}
// split 8 f32 (two f32x4v) into hi/lo bf16x8 packed as i32x4v
__device__ __forceinline__ void split8(f32x4v a, f32x4v b, i32x4v& hi, i32x4v& lo) {
  float v[8] = {a[0], a[1], a[2], a[3], b[0], b[1], b[2], b[3]};
  unsigned int h[8], l[8];
#pragma unroll
  for (int j = 0; j < 8; ++j) {
    h[j] = f2bf(v[j]);
    l[j] = f2bf(v[j] - bf2f(h[j]));
  }
  hi[0] = (int)(h[0] | (h[1] << 16)); hi[1] = (int)(h[2] | (h[3] << 16));
  hi[2] = (int)(h[4] | (h[5] << 16)); hi[3] = (int)(h[6] | (h[7] << 16));
  lo[0] = (int)(l[0] | (l[1] << 16)); lo[1] = (int)(l[2] | (l[3] << 16));
  lo[2] = (int)(l[4] | (l[5] << 16)); lo[3] = (int)(l[6] | (l[7] << 16));
}
__device__ __forceinline__ void mfma_bf16(f32x4v& acc, i32x4v a, i32x4v b) {
  asm("v_mfma_f32_16x16x32_bf16 %0, %1, %2, %0" : "+v"(acc) : "v"(a), "v"(b));
}

__device__ __forceinline__ int trow(int f, int i) {
  return (f < 3) ? (f + 9 * i) : (f + 2 * (i % 3) + 9 * (i / 3));
}

// ---------------------------------------------------------------------------
// Prep via MFMA, 3-term bf16 split. grid = 3 tensors * 5 f * 16 Mblk = 240,
// block = 256 (4 waves). Stage: W f32 [32 o][512 k] -> bf16 hi/lo in swizzled
// LDS (W read from HBM exactly once). Waves: (msub = o-half, stripe) iterate
// row-tiles of the class; x converted to bf16 hi/lo in registers per k-step.
__global__ __launch_bounds__(256) void prep_mfma_kernel(
    const float* __restrict__ Xq, const float* __restrict__ Xk, const float* __restrict__ Xv,
    const float* __restrict__ Wq, const float* __restrict__ Wk, const float* __restrict__ Wv,
    const float* __restrict__ Bq, const float* __restrict__ Bk, const float* __restrict__ Bv,
    float* __restrict__ Yq, float* __restrict__ Yk, float* __restrict__ Yv) {
  __shared__ unsigned short ldsw[2][32][HH];  // 64 KB: [hi/lo][o][k]

  const int bid = blockIdx.x;
  const int tensor = bid / 80, rem = bid % 80;
  const int f = rem >> 4, Mblk = rem & 15;
  const int count = (f < 3) ? 57 : 171;
  const int ng = 2 * count;

  const float* X  = (tensor == 0) ? Xq : (tensor == 1) ? Xk : Xv;
  const float* W  = (tensor == 0) ? Wq : (tensor == 1) ? Wk : Wv;
  const float* Bi = (tensor == 0) ? Bq : (tensor == 1) ? Bk : Bv;
  float* Y        = (tensor == 0) ? Yq : (tensor == 1) ? Yk : Yv;

  const int tid = threadIdx.x;
  const float* Wslice = W + ((size_t)f * HH + Mblk * 32) * HH;
  unsigned short* lds0 = &ldsw[0][0][0];

  // ---- stage + convert W (each element read once from HBM) ----
  {
    const int o = tid >> 3, kc = tid & 7;
#pragma unroll
    for (int u = 0; u < 8; ++u) {
      const int k = kc * 64 + u * 8;
      f32x4v a = *(const f32x4v*)(Wslice + o * HH + k);
      f32x4v b = *(const f32x4v*)(Wslice + o * HH + k + 4);
      i32x4v hi, lo;
      split8(a, b, hi, lo);
      const int idx = ((o * HH + k) ^ ((o & 7) << 3));  // ushort index; ^(o&7)*8 = 16B swizzle
      *(i32x4v*)(lds0 + idx) = hi;
      *(i32x4v*)(lds0 + 32 * HH + idx) = lo;
    }
  }
  __syncthreads();

  const int wid = tid >> 6, l = tid & 63;
  const int msub = wid & 1, stripe = wid >> 1;
  const int m = l & 15, kq = l >> 4;
  const int obase = Mblk * 32 + msub * 16;
  const int oA = msub * 16 + m;          // LDS row for A fragment
  const int swz = (oA & 7) << 3;         // ushort-index swizzle

  // bias: sum of 5 class biases at this lane's 4 output columns
  f32x4v bias = {0.f, 0.f, 0.f, 0.f};
#pragma unroll
  for (int ff = 0; ff < 5; ++ff) {
    const float* bp = Bi + ff * HH + obase + kq * 4;
    bias[0] += bp[0]; bias[1] += bp[1]; bias[2] += bp[2]; bias[3] += bp[3];
  }

  const int Nt = (f < 3) ? 8 : 22;
  for (int nt = stripe; nt < Nt; nt += 2) {
    const int gi = nt * 16 + m;
    const bool valid = gi < ng;
    const int b = (gi >= count) ? 1 : 0;
    const int i = valid ? (gi - b * count) : 0;
    const int t = trow(f, i);
    const float* xrow = X + (size_t)((valid ? b : 0) * SS + t) * HH + kq * 8;

    f32x4v acc0 = {0.f, 0.f, 0.f, 0.f};
    f32x4v acc1 = {0.f, 0.f, 0.f, 0.f};
    f32x4v acc2 = {0.f, 0.f, 0.f, 0.f};
#pragma unroll
    for (int ks = 0; ks < 16; ++ks) {
      const int idxA = ((oA * HH + ks * 32 + kq * 8) ^ swz);
      i32x4v ahi = *(const i32x4v*)(lds0 + idxA);
      i32x4v alo = *(const i32x4v*)(lds0 + 32 * HH + idxA);
      f32x4v xa = valid ? *(const f32x4v*)(xrow + ks * 32) : (f32x4v){0.f, 0.f, 0.f, 0.f};
      f32x4v xb = valid ? *(const f32x4v*)(xrow + ks * 32 + 4) : (f32x4v){0.f, 0.f, 0.f, 0.f};
      i32x4v bhi, blo;
      split8(xa, xb, bhi, blo);
      mfma_bf16(acc0, ahi, bhi);
      mfma_bf16(acc1, ahi, blo);
      mfma_bf16(acc2, alo, bhi);
    }
    if (valid) {
      f32x4v r = acc0 + acc1 + acc2 + bias;
      *(f32x4v*)(Y + (size_t)(b * SS + t) * HH + obase + kq * 4) = r;
    }
  }
}

// ---------------------------------------------------------------------------
// Fused: blocks 0..31 = partial V-sum; block 32 = graph layout detect.
__global__ __launch_bounds__(256) void vsum_detect_kernel(
    const float* __restrict__ V, float* __restrict__ part,
    const uint4* __restrict__ gv, int* __restrict__ flag) {
  if (blockIdx.x < 32) {
    int idx = (blockIdx.x & 3) * 256 + threadIdx.x;
    int p = blockIdx.x >> 2;
    int b = idx >> 9, o = idx & 511;
    float acc = 0.f;
    for (int t = p; t < SS; t += 8)
      acc += V[(size_t)(b * SS + t) * HH + o];
    part[p * 1024 + idx] = acc;
  } else {
    __shared__ int s;
    if (threadIdx.x == 0) s = 0;
    __syncthreads();
    unsigned int local = 0;
    for (int i = threadIdx.x; i < 2048; i += 256) {  // 32 KB scan
      uint4 v = gv[i];
      local |= (v.x | v.y | v.z | v.w) & 0x0000ff00u;
    }
    if (local) atomicOr(&s, 1);
    __syncthreads();
    if (threadIdx.x == 0) *flag = s;
  }
}

// ---------------------------------------------------------------------------
// Fused attention: blocks [0,1020) sparse q>=3; blocks [1020,1836) dense scores.
__global__ __launch_bounds__(256) void attn_fused_kernel(
    const float* __restrict__ Q, const float* __restrict__ K, const float* __restrict__ V,
    const float* __restrict__ vsumPart, const void* __restrict__ graph,
    const int* __restrict__ flag,
    const float* __restrict__ EK, const float* __restrict__ EV, const float* __restrict__ EQ,
    float* __restrict__ X, float* __restrict__ sWS) {
  __shared__ float sQ[HH];
  __shared__ float sW[5 * NHH];
  __shared__ float sRed[4 * 64];
  __shared__ int sUni;

  const int tid = threadIdx.x, lane = tid & 63, wv = tid >> 6;
  const int isBool = *flag;

  if (blockIdx.x < 1020) {
    // ---------------- sparse path ----------------
    const int bid = blockIdx.x;
    const int b = bid / 510, q = 3 + bid % 510;
    const int row = b * SS + q;

    sQ[tid] = Q[(size_t)row * HH + tid];
    sQ[tid + 256] = Q[(size_t)row * HH + tid + 256];
    if (tid == 0) sUni = 0;
    __syncthreads();

    const int g = 3 + ((q - 3) >> 1) * 2;
    const size_t gbase = (size_t)b * SS * SS + (size_t)q * SS;
    const int h = lane >> 3, dg = lane & 7, d0 = dg * 8;

    for (int c = wv; c < 5; c += 4) {
      int k = (c < 3) ? c : g + (c - 3);
      bool m = graph_at(graph, isBool, gbase + k);
      const float* ekp = EK + (gbase + k) * DDIM + d0;
      const float* eqp = EQ + ((size_t)(b * SS + k) * SS + q) * DDIM + d0;
      const float* kp  = K + (size_t)(b * SS + k) * HH + h * 64 + d0;
      const float* qp  = &sQ[h * 64 + d0];
      float4 ek0 = *(const float4*)ekp, ek1 = *(const float4*)(ekp + 4);
      float4 eq0 = *(const float4*)eqp, eq1 = *(const float4*)(eqp + 4);
      float4 kk0 = *(const float4*)kp,  kk1 = *(const float4*)(kp + 4);
      float4 qq0 = *(const float4*)qp,  qq1 = *(const float4*)(qp + 4);
      float p = dot4(add4(qq0, eq0), add4(kk0, ek0)) + dot4(add4(qq1, eq1), add4(kk1, ek1));
      p += __shfl_xor(p, 1);
      p += __shfl_xor(p, 2);
      p += __shfl_xor(p, 4);
      if (dg == 0) sW[c * NHH + h] = m ? p * 0.125f : -1e30f;
    }
    __syncthreads();

    if (wv == 0) {
      int hh = lane >> 3, c = lane & 7;
      float s = (c < 5) ? sW[c * NHH + hh] : -1e30f;
      float mx = s;
#pragma unroll
      for (int off = 4; off; off >>= 1) mx = fmaxf(mx, __shfl_xor(mx, off));
      float e = (mx < -1e29f) ? 0.f : __expf(s - mx);
      float sum = e;
#pragma unroll
      for (int off = 4; off; off >>= 1) sum += __shfl_xor(sum, off);
      if (c < 5) sW[c * NHH + hh] = (mx < -1e29f) ? 0.f : e / sum;
      if (lane == 0 && mx < -1e29f) sUni = 1;
    }
    __syncthreads();

    if (sUni) {
      float acc = 0.f;
      for (int k = wv; k < SS; k += 4)
        acc += EV[(gbase + k) * DDIM + lane];
      sRed[wv * 64 + lane] = acc;
      __syncthreads();
      if (tid < 64) sRed[tid] = sRed[tid] + sRed[64 + tid] + sRed[128 + tid] + sRed[192 + tid];
      __syncthreads();
      const float c0 = 1.0f / 513.0f;
      for (int o = tid; o < HH; o += 256) {
        float vs = 0.f;
#pragma unroll
        for (int p = 0; p < 8; ++p) vs += vsumPart[p * 1024 + b * HH + o];
        X[(size_t)row * HH + o] = (vs + sRed[o & 63]) * c0;
      }
    } else {
#pragma unroll
      for (int rep = 0; rep < 2; ++rep) {
        int o = tid + rep * 256;
        int hh = o >> 6, d = o & 63;
        float acc = 0.f;
#pragma unroll
        for (int c = 0; c < 5; ++c) {
          int k = (c < 3) ? c : g + (c - 3);
          acc += sW[c * NHH + hh] *
                 (V[(size_t)(b * SS + k) * HH + o] + EV[(gbase + k) * DDIM + d]);
        }
        X[(size_t)row * HH + o] = acc;
      }
    }
  } else {
    // ---------------- dense score path (q < 3) ----------------
    const int bid = blockIdx.x - 1020;
    const int bqh = bid / 17, ks = bid % 17;
    const int b = bqh / 24, r = bqh % 24, q = r >> 3, hd = r & 7;
    const int kk = lane >> 3, dg = lane & 7, d0 = dg * 8;
    const int k = ks * 32 + wv * 8 + kk;
    const int kc = (k < SS) ? k : (SS - 1);
    const size_t gbase = (size_t)b * SS * SS + (size_t)q * SS;
    const bool m = (k < SS) && graph_at(graph, isBool, gbase + kc);

    const float* qp  = Q + (size_t)(b * SS + q) * HH + hd * 64 + d0;
    const float* ekp = EK + (gbase + kc) * DDIM + d0;
    const float* eqp = EQ + ((size_t)(b * SS + kc) * SS + q) * DDIM + d0;
    const float* kp  = K + (size_t)(b * SS + kc) * HH + hd * 64 + d0;
    float4 qq0 = *(const float4*)qp,  qq1 = *(const float4*)(qp + 4);
    float4 ek0 = *(const float4*)ekp, ek1 = *(const float4*)(ekp + 4);
    float4 eq0 = *(const float4*)eqp, eq1 = *(const float4*)(eqp + 4);
    float4 kk0 = *(const float4*)kp,  kk1 = *(const float4*)(kp + 4);
    float p = dot4(add4(qq0, eq0), add4(kk0, ek0)) + dot4(add4(qq1, eq1), add4(kk1, ek1));
    p += __shfl_xor(p, 1);
    p += __shfl_xor(p, 2);
    p += __shfl_xor(p, 4);
    if (dg == 0 && k < SS)
      sWS[(size_t)bqh * SS + k] = m ? p * 0.125f : -1e30f;
  }
}

// ---------------------------------------------------------------------------
// Dense finish: softmax + PV + combine, one block (1024 thr) per (b,q,h) = 48.
__global__ __launch_bounds__(1024) void dense_finish_kernel(
    const float* __restrict__ V, const float* __restrict__ EV,
    const float* __restrict__ sWS, float* __restrict__ X) {
  __shared__ float red[16];
  __shared__ float sP[SS];
  __shared__ float sOut[16][DDIM];

  const int bqh = blockIdx.x;
  const int b = bqh / 24, r2 = bqh % 24, q = r2 >> 3, hd = r2 & 7;
  const int tid = threadIdx.x, lane = tid & 63, wv = tid >> 6;
  const float* s = sWS + (size_t)bqh * SS;

  const float v = (tid < SS) ? s[tid] : -3e38f;
  float mx = v;
#pragma unroll
  for (int off = 32; off; off >>= 1) mx = fmaxf(mx, __shfl_xor(mx, off));
  if (lane == 0) red[wv] = mx;
  __syncthreads();
  float mxAll = -3e38f;
#pragma unroll
  for (int j = 0; j < 16; ++j) mxAll = fmaxf(mxAll, red[j]);

  float p;
  if (mxAll < -1e29f) {
    p = 1.0f / 513.0f;  // uniform over all keys
  } else {
    float e = (tid < SS) ? __expf(v - mxAll) : 0.f;
    float sm = e;
#pragma unroll
    for (int off = 32; off; off >>= 1) sm += __shfl_xor(sm, off);
    __syncthreads();
    if (lane == 0) red[wv] = sm;
    __syncthreads();
    float tot = 0.f;
#pragma unroll
    for (int j = 0; j < 16; ++j) tot += red[j];
    p = e / tot;
  }
  if (tid < SS) sP[tid] = p;
  __syncthreads();

  const int d = tid & 63, kc = tid >> 6;
  const size_t evb = ((size_t)(b * SS + q) * SS) * DDIM;
  float acc = 0.f;
  for (int k = kc; k < SS; k += 16)
    acc += sP[k] * (V[(size_t)(b * SS + k) * HH + hd * 64 + d] +
                    EV[evb + (size_t)k * DDIM + d]);
  sOut[kc][d] = acc;
  __syncthreads();
  if (tid < 64) {
    float t = 0.f;
#pragma unroll
    for (int j = 0; j < 16; ++j) t += sOut[j][tid];
    X[(size_t)(b * SS + q) * HH + hd * 64 + tid] = t;
  }
}

// ---------------------------------------------------------------------------
// Output projection via MFMA, same machinery as prep. grid = 16 Mblk * 8 = 128.
__global__ __launch_bounds__(256) void proj_mfma_kernel(
    const float* __restrict__ Xin, const float* __restrict__ Wo,
    const float* __restrict__ bo, float* __restrict__ out) {
  __shared__ unsigned short ldsw[2][32][HH];  // 64 KB

  const int bid = blockIdx.x;
  const int Mblk = bid >> 3, nsp = bid & 7;
  const int tid = threadIdx.x;
  const float* Wslice = Wo + (size_t)(Mblk * 32) * HH;
  unsigned short* lds0 = &ldsw[0][0][0];

  {
    const int o = tid >> 3, kc = tid & 7;
#pragma unroll
    for (int u = 0; u < 8; ++u) {
      const int k = kc * 64 + u * 8;
      f32x4v a = *(const f32x4v*)(Wslice + o * HH + k);
      f32x4v b = *(const f32x4v*)(Wslice + o * HH + k + 4);
      i32x4v hi, lo;
      split8(a, b, hi, lo);
      const int idx = ((o * HH + k) ^ ((o & 7) << 3));
      *(i32x4v*)(lds0 + idx) = hi;
      *(i32x4v*)(lds0 + 32 * HH + idx) = lo;
    }
  }
  __syncthreads();

  const int wid = tid >> 6, l = tid & 63;
  const int msub = wid & 1, stripe = wid >> 1;
  const int m = l & 15, kq = l >> 4;
  const int obase = Mblk * 32 + msub * 16;
  const int oA = msub * 16 + m;
  const int swz = (oA & 7) << 3;
  const int NROW = BB * SS;  // 1026

  f32x4v bias;
  {
    const float* bp = bo + obase + kq * 4;
    bias[0] = bp[0]; bias[1] = bp[1]; bias[2] = bp[2]; bias[3] = bp[3];
  }

  const int start = nsp * 9, end = (start + 9 < 65) ? start + 9 : 65;
  for (int nt = start + stripe; nt < end; nt += 2) {
    const int gi = nt * 16 + m;
    const bool valid = gi < NROW;
    const float* xrow = Xin + (size_t)(valid ? gi : 0) * HH + kq * 8;

    f32x4v acc0 = {0.f, 0.f, 0.f, 0.f};
    f32x4v acc1 = {0.f, 0.f, 0.f, 0.f};
    f32x4v acc2 = {0.f, 0.f, 0.f, 0.f};
#pragma unroll
    for (int ks = 0; ks < 16; ++ks) {
      const int idxA = ((oA * HH + ks * 32 + kq * 8) ^ swz);
      i32x4v ahi = *(const i32x4v*)(lds0 + idxA);
      i32x4v alo = *(const i32x4v*)(lds0 + 32 * HH + idxA);
      f32x4v xa = valid ? *(const f32x4v*)(xrow + ks * 32) : (f32x4v){0.f, 0.f, 0.f, 0.f};
      f32x4v xb = valid ? *(const f32x4v*)(xrow + ks * 32 + 4) : (f32x4v){0.f, 0.f, 0.f, 0.f};
      i32x4v bhi, blo;
      split8(xa, xb, bhi, blo);
      mfma_bf16(acc0, ahi, bhi);
      mfma_bf16(acc1, ahi, blo);
      mfma_bf16(acc2, alo, bhi);
    }
    if (valid) {
      f32x4v r = acc0 + acc1 + acc2 + bias;
      *(f32x4v*)(out + (size_t)gi * HH + obase + kq * 4) = r;
    }
  }
}

// ---------------------------------------------------------------------------
extern "C" void kernel_launch(void* const* d_in, const int* in_sizes, int n_in,
                              void* d_out, int out_size, void* d_ws, size_t ws_size,
                              hipStream_t stream) {
  (void)in_sizes; (void)n_in; (void)out_size; (void)ws_size;
  const float* query = (const float*)d_in[0];
  const float* key   = (const float*)d_in[1];
  const float* value = (const float*)d_in[2];
  const void*  graph = d_in[3];
  const float* EK = (const float*)d_in[4];
  const float* EV = (const float*)d_in[5];
  const float* EQ = (const float*)d_in[6];
  const float* Wq = (const float*)d_in[7];
  const float* bq = (const float*)d_in[8];
  const float* Wk = (const float*)d_in[9];
  const float* bk = (const float*)d_in[10];
  const float* Wv = (const float*)d_in[11];
  const float* bv = (const float*)d_in[12];
  const float* Wo = (const float*)d_in[13];
  const float* bo = (const float*)d_in[14];
  float* out = (float*)d_out;

  char* ws = (char*)d_ws;
  int*   flag = (int*)ws;                        // 4 B
  float* part = (float*)(ws + 256);              // 32 KB
  float* Qp = (float*)(ws + 40960);              // 2101248 B each
  float* Kp = (float*)(ws + 40960 + 2101248);
  float* Vp = (float*)(ws + 40960 + 2 * 2101248);
  float* Xp = (float*)(ws + 40960 + 3 * 2101248);
  float* sWS = (float*)(ws + 40960 + 4 * 2101248);  // 98496 B

  prep_mfma_kernel<<<240, 256, 0, stream>>>(query, key, value, Wq, Wk, Wv,
                                            bq, bk, bv, Qp, Kp, Vp);
  vsum_detect_kernel<<<33, 256, 0, stream>>>(Vp, part, (const uint4*)graph, flag);
  attn_fused_kernel<<<1020 + 48 * 17, 256, 0, stream>>>(Qp, Kp, Vp, part, graph, flag,
                                                        EK, EV, EQ, Xp, sWS);
  dense_finish_kernel<<<48, 1024, 0, stream>>>(Vp, EV, sWS, Xp);
  proj_mfma_kernel<<<128, 256, 0, stream>>>(Xp, Wo, bo, out);
}

// Round 10
// 111.581 us; speedup vs baseline: 2.0895x; 2.0895x over previous
//
#include <hip/hip_runtime.h>
#include <hip/hip_bf16.h>

#define BB 2
#define SS 513
#define HH 512
#define NHH 8
#define DDIM 64

typedef float f32x4v __attribute__((ext_vector_type(4)));
typedef int i32x4v __attribute__((ext_vector_type(4)));
typedef unsigned short ushort_t;

// ---- workspace offsets (bytes) ----
#define OFF_PART   256
#define OFF_QP     40960
#define OFF_KP     (40960 + 2101248)
#define OFF_VP     (40960 + 2 * 2101248)
#define OFF_XPP    (40960 + 3 * 2101248)
#define OFF_SWS    (40960 + 4 * 2101248)            // 8445952
#define OFF_WBF    8544512                           // 16 tf * 1MB = 16777216
#define OFF_XBFP   (8544512 + 16777216)              // 25321728, 3*68*32768 = 6684672
#define OFF_XBFO   (25321728 + 6684672)              // 32006400, 66*32768 = 2162688
#define WS_NEED    (32006400ULL + 2162688ULL)        // 34169088

__device__ __forceinline__ float dot4(float4 a, float4 b) {
  return a.x * b.x + a.y * b.y + a.z * b.z + a.w * b.w;
}
__device__ __forceinline__ float4 add4(float4 a, float4 b) {
  return make_float4(a.x + b.x, a.y + b.y, a.z + b.z, a.w + b.w);
}

#define DPP_ADD(v, ctrl) \
  ((v) + __int_as_float(__builtin_amdgcn_update_dpp( \
             0, __float_as_int(v), (ctrl), 0xF, 0xF, true)))
__device__ __forceinline__ float kg_reduce8(float v) {
  v = DPP_ADD(v, 0xB1);
  v = DPP_ADD(v, 0x4E);
  v = DPP_ADD(v, 0x141);
  return v;
}

__device__ __forceinline__ bool graph_at(const void* g, int isBool, size_t idx) {
  if (isBool) return ((const unsigned char*)g)[idx] != 0;
  return ((const int*)g)[idx] != 0;
}

// ---- bf16 helpers (RNE) — numerics verified in round 9 ----
__device__ __forceinline__ unsigned int f2bf(float f) {
  unsigned int u = __float_as_uint(f);
  return (u + 0x7FFFu + ((u >> 16) & 1u)) >> 16;
}
__device__ __forceinline__ float bf2f(unsigned int h) {
  return __uint_as_float(h << 16);
}
__device__ __forceinline__ void split8(f32x4v a, f32x4v b, i32x4v& hi, i32x4v& lo) {
  float v[8] = {a[0], a[1], a[2], a[3], b[0], b[1], b[2], b[3]};
  unsigned int h[8], l[8];
#pragma unroll
  for (int j = 0; j < 8; ++j) {
    h[j] = f2bf(v[j]);
    l[j] = f2bf(v[j] - bf2f(h[j]));
  }
  hi[0] = (int)(h[0] | (h[1] << 16)); hi[1] = (int)(h[2] | (h[3] << 16));
  hi[2] = (int)(h[4] | (h[5] << 16)); hi[3] = (int)(h[6] | (h[7] << 16));
  lo[0] = (int)(l[0] | (l[1] << 16)); lo[1] = (int)(l[2] | (l[3] << 16));
  lo[2] = (int)(l[4] | (l[5] << 16)); lo[3] = (int)(l[6] | (l[7] << 16));
}
__device__ __forceinline__ void mfma_bf16(f32x4v& acc, i32x4v a, i32x4v b) {
  asm("v_mfma_f32_16x16x32_bf16 %0, %1, %2, %0" : "+v"(acc) : "v"(a), "v"(b));
}

__device__ __forceinline__ int trow(int f, int i) {
  return (f < 3) ? (f + 9 * i) : (f + 2 * (i % 3) + 9 * (i / 3));
}
__device__ __forceinline__ int toff_of(int f) {
  return f == 0 ? 0 : f == 1 ? 8 : f == 2 ? 16 : f == 3 ? 24 : 46;
}

// ---------------------------------------------------------------------------
// Convert W (15 prep slices + Wo as tf=15) -> fragment-ordered bf16 hi/lo.
// Fragment layout per (tf, mt): [ks 16][half 2][lane 64][8], lane = kq*16+m,
// element = W[mt*16+m][ks*32+kq*8+j]. grid = 2048, block = 256.
__global__ __launch_bounds__(256) void conv_w_kernel(
    const float* __restrict__ Wq, const float* __restrict__ Wk,
    const float* __restrict__ Wv, const float* __restrict__ Wo,
    ushort_t* __restrict__ WBF) {
  const int idx = blockIdx.x * 256 + threadIdx.x;   // 16*512*64 = 524288
  const int tf = idx >> 15, rem = idx & 32767;
  const int o = rem >> 6, kc = rem & 63;
  const float* wrow;
  if (tf < 15) {
    const int t = tf / 5, f = tf % 5;
    const float* W = (t == 0) ? Wq : (t == 1) ? Wk : Wv;
    wrow = W + ((size_t)f * HH + o) * HH;
  } else {
    wrow = Wo + (size_t)o * HH;
  }
  f32x4v a = *(const f32x4v*)(wrow + kc * 8);
  f32x4v b = *(const f32x4v*)(wrow + kc * 8 + 4);
  i32x4v hi, lo;
  split8(a, b, hi, lo);
  const int mt = o >> 4, m = o & 15, ks = kc >> 2, kq = kc & 3;
  const int l = kq * 16 + m;
  const size_t base = (size_t)tf * 524288 + (size_t)mt * 16384 + ks * 1024 + l * 8;
  *(i32x4v*)(WBF + base) = hi;
  *(i32x4v*)(WBF + base + 512) = lo;
}

// ---------------------------------------------------------------------------
// Convert X (q,k,v), class-grouped + padded to 16-row tiles -> bf16 fragments.
// Per (t): 68 tiles (f offsets 0,8,16,24,46). grid = 816, block = 256.
__global__ __launch_bounds__(256) void conv_x_kernel(
    const float* __restrict__ Xq, const float* __restrict__ Xk,
    const float* __restrict__ Xv, ushort_t* __restrict__ XBF) {
  const int idx = blockIdx.x * 256 + threadIdx.x;   // 3*1088*64 = 208896
  const int t = idx / 69632, rem = idx % 69632;
  const int prow = rem >> 6, kc = rem & 63;
  int f, gi;
  if (prow < 128)      { f = 0; gi = prow; }
  else if (prow < 256) { f = 1; gi = prow - 128; }
  else if (prow < 384) { f = 2; gi = prow - 256; }
  else if (prow < 736) { f = 3; gi = prow - 384; }
  else                 { f = 4; gi = prow - 736; }
  const int count = (f < 3) ? 57 : 171, ng = 2 * count;
  f32x4v a = {0.f, 0.f, 0.f, 0.f}, b = {0.f, 0.f, 0.f, 0.f};
  if (gi < ng) {
    const int bb = (gi >= count) ? 1 : 0, i = gi - bb * count;
    const int tr = trow(f, i);
    const float* X = (t == 0) ? Xq : (t == 1) ? Xk : Xv;
    const float* xr = X + (size_t)(bb * SS + tr) * HH + kc * 8;
    a = *(const f32x4v*)xr;
    b = *(const f32x4v*)(xr + 4);
  }
  i32x4v hi, lo;
  split8(a, b, hi, lo);
  const int nt = gi >> 4, n = gi & 15, ks = kc >> 2, kq = kc & 3;
  const int l = kq * 16 + n;
  const size_t base = (size_t)(t * 68 + toff_of(f) + nt) * 16384 + ks * 1024 + l * 8;
  *(i32x4v*)(XBF + base) = hi;
  *(i32x4v*)(XBF + base + 512) = lo;
}

// ---------------------------------------------------------------------------
// Convert attention output Xp (1026 rows, padded to 1056) -> bf16 fragments.
// grid = 264, block = 256.
__global__ __launch_bounds__(256) void conv_xo_kernel(const float* __restrict__ Xp,
                                                      ushort_t* __restrict__ XBF) {
  const int idx = blockIdx.x * 256 + threadIdx.x;   // 1056*64 = 67584
  const int prow = idx >> 6, kc = idx & 63;
  f32x4v a = {0.f, 0.f, 0.f, 0.f}, b = {0.f, 0.f, 0.f, 0.f};
  if (prow < BB * SS) {
    const float* xr = Xp + (size_t)prow * HH + kc * 8;
    a = *(const f32x4v*)xr;
    b = *(const f32x4v*)(xr + 4);
  }
  i32x4v hi, lo;
  split8(a, b, hi, lo);
  const int nt = prow >> 4, n = prow & 15, ks = kc >> 2, kq = kc & 3;
  const int l = kq * 16 + n;
  const size_t base = (size_t)nt * 16384 + ks * 1024 + l * 8;
  *(i32x4v*)(XBF + base) = hi;
  *(i32x4v*)(XBF + base + 512) = lo;
}

// ---------------------------------------------------------------------------
// Prep GEMM: 3-term bf16 MFMA. Block = (t,f, 2 N-tiles staged in LDS, M-half).
// Wave = 4 M-tiles x 2 N-tiles. XCD-pinned decode (bid&7). grid = 208.
__global__ __launch_bounds__(256) void gemm_prep_kernel(
    const ushort_t* __restrict__ WBF, const ushort_t* __restrict__ XBF,
    const float* __restrict__ Bq, const float* __restrict__ Bk,
    const float* __restrict__ Bv,
    float* __restrict__ Yq, float* __restrict__ Yk, float* __restrict__ Yv) {
  __shared__ ushort_t sX[32768];  // 64 KB: two 16-row K=512 hi/lo tiles

  const int xcd = blockIdx.x & 7, slot = blockIdx.x >> 3;
  int t, f, nb, mh;
  if (xcd < 6 && slot < 22) {
    t = xcd >> 1; f = 3 + (xcd & 1); nb = slot >> 1; mh = slot & 1;
  } else {
    int id;
    if (xcd < 6) {
      id = xcd * 4 + (slot - 22);
    } else {
      if (slot >= 24) return;
      id = 24 + (xcd - 6) * 24 + slot;
    }
    const int s = id >> 3, j = id & 7;
    t = s / 3; f = s % 3; nb = j >> 1; mh = j & 1;
  }
  const int count = (f < 3) ? 57 : 171, ng = 2 * count;
  const int tid = threadIdx.x;

  const ushort_t* src = XBF + (size_t)(t * 68 + toff_of(f) + nb * 2) * 16384;
#pragma unroll
  for (int u = 0; u < 16; ++u) {
    const int c = (u * 256 + tid) * 8;
    *(i32x4v*)(sX + c) = *(const i32x4v*)(src + c);
  }
  __syncthreads();

  const int wid = tid >> 6, l = tid & 63, kq = l >> 4, col = l & 15;
  const int tf = t * 5 + f;
  const int mt0 = mh * 16 + wid * 4;
  const ushort_t* Abase = WBF + (size_t)tf * 524288 + (size_t)mt0 * 16384;

  f32x4v acc0[4][2], acc1[4][2];
#pragma unroll
  for (int w = 0; w < 4; ++w)
#pragma unroll
    for (int tau = 0; tau < 2; ++tau) {
      acc0[w][tau] = (f32x4v){0.f, 0.f, 0.f, 0.f};
      acc1[w][tau] = (f32x4v){0.f, 0.f, 0.f, 0.f};
    }

#pragma unroll
  for (int ks = 0; ks < 16; ++ks) {
    const ushort_t* b0 = sX + ks * 1024 + l * 8;
    i32x4v bhi0 = *(const i32x4v*)b0;
    i32x4v blo0 = *(const i32x4v*)(b0 + 512);
    i32x4v bhi1 = *(const i32x4v*)(b0 + 16384);
    i32x4v blo1 = *(const i32x4v*)(b0 + 16384 + 512);
#pragma unroll
    for (int w = 0; w < 4; ++w) {
      const ushort_t* ap = Abase + (size_t)w * 16384 + ks * 1024 + l * 8;
      i32x4v ahi = *(const i32x4v*)ap;
      i32x4v alo = *(const i32x4v*)(ap + 512);
      mfma_bf16(acc0[w][0], ahi, bhi0);
      mfma_bf16(acc1[w][0], ahi, blo0);
      mfma_bf16(acc1[w][0], alo, bhi0);
      mfma_bf16(acc0[w][1], ahi, bhi1);
      mfma_bf16(acc1[w][1], ahi, blo1);
      mfma_bf16(acc1[w][1], alo, bhi1);
    }
  }

  const float* Bi = (t == 0) ? Bq : (t == 1) ? Bk : Bv;
  float* Y = (t == 0) ? Yq : (t == 1) ? Yk : Yv;
#pragma unroll
  for (int w = 0; w < 4; ++w) {
    const int o0 = (mt0 + w) * 16 + kq * 4;
    f32x4v bs = {0.f, 0.f, 0.f, 0.f};
#pragma unroll
    for (int ff = 0; ff < 5; ++ff) bs += *(const f32x4v*)(Bi + ff * HH + o0);
#pragma unroll
    for (int tau = 0; tau < 2; ++tau) {
      const int gi = (nb * 2 + tau) * 16 + col;
      if (gi < ng) {
        const int bb = (gi >= count) ? 1 : 0, i = gi - bb * count;
        const int tr = trow(f, i);
        f32x4v r = acc0[w][tau] + acc1[w][tau] + bs;
        *(f32x4v*)(Y + (size_t)(bb * SS + tr) * HH + o0) = r;
      }
    }
  }
}

// ---------------------------------------------------------------------------
// Proj GEMM: same machinery, Wo = tf 15. grid = 66 (33 nb x 2 mh).
__global__ __launch_bounds__(256) void gemm_proj_kernel(
    const ushort_t* __restrict__ WBF, const ushort_t* __restrict__ XBF,
    const float* __restrict__ bo, float* __restrict__ out) {
  __shared__ ushort_t sX[32768];
  const int nb = blockIdx.x >> 1, mh = blockIdx.x & 1;
  const int tid = threadIdx.x;
  const ushort_t* src = XBF + (size_t)nb * 32768;
#pragma unroll
  for (int u = 0; u < 16; ++u) {
    const int c = (u * 256 + tid) * 8;
    *(i32x4v*)(sX + c) = *(const i32x4v*)(src + c);
  }
  __syncthreads();

  const int wid = tid >> 6, l = tid & 63, kq = l >> 4, col = l & 15;
  const int mt0 = mh * 16 + wid * 4;
  const ushort_t* Abase = WBF + (size_t)15 * 524288 + (size_t)mt0 * 16384;

  f32x4v acc0[4][2], acc1[4][2];
#pragma unroll
  for (int w = 0; w < 4; ++w)
#pragma unroll
    for (int tau = 0; tau < 2; ++tau) {
      acc0[w][tau] = (f32x4v){0.f, 0.f, 0.f, 0.f};
      acc1[w][tau] = (f32x4v){0.f, 0.f, 0.f, 0.f};
    }

#pragma unroll
  for (int ks = 0; ks < 16; ++ks) {
    const ushort_t* b0 = sX + ks * 1024 + l * 8;
    i32x4v bhi0 = *(const i32x4v*)b0;
    i32x4v blo0 = *(const i32x4v*)(b0 + 512);
    i32x4v bhi1 = *(const i32x4v*)(b0 + 16384);
    i32x4v blo1 = *(const i32x4v*)(b0 + 16384 + 512);
#pragma unroll
    for (int w = 0; w < 4; ++w) {
      const ushort_t* ap = Abase + (size_t)w * 16384 + ks * 1024 + l * 8;
      i32x4v ahi = *(const i32x4v*)ap;
      i32x4v alo = *(const i32x4v*)(ap + 512);
      mfma_bf16(acc0[w][0], ahi, bhi0);
      mfma_bf16(acc1[w][0], ahi, blo0);
      mfma_bf16(acc1[w][0], alo, bhi0);
      mfma_bf16(acc0[w][1], ahi, bhi1);
      mfma_bf16(acc1[w][1], ahi, blo1);
      mfma_bf16(acc1[w][1], alo, bhi1);
    }
  }

#pragma unroll
  for (int w = 0; w < 4; ++w) {
    const int o0 = (mt0 + w) * 16 + kq * 4;
    const f32x4v bs = *(const f32x4v*)(bo + o0);
#pragma unroll
    for (int tau = 0; tau < 2; ++tau) {
      const int gi = nb * 32 + tau * 16 + col;
      if (gi < BB * SS) {
        f32x4v r = acc0[w][tau] + acc1[w][tau] + bs;
        *(f32x4v*)(out + (size_t)gi * HH + o0) = r;
      }
    }
  }
}

// ---------------------------------------------------------------------------
// FALLBACK (ws too small): round-8 f32 prep, XCD-pinned. grid = 480, block 1024.
__global__ __launch_bounds__(1024) void prep_f32_kernel(
    const float* __restrict__ Xq, const float* __restrict__ Xk, const float* __restrict__ Xv,
    const float* __restrict__ Wq, const float* __restrict__ Wk, const float* __restrict__ Wv,
    const float* __restrict__ Bq, const float* __restrict__ Bk, const float* __restrict__ Bv,
    float* __restrict__ Yq, float* __restrict__ Yk, float* __restrict__ Yv) {
  __shared__ float xs[8][HH];
  const int xcd = blockIdx.x & 7;
  const int slot = blockIdx.x >> 3;
  int tensor, f, chunk, b;
  if (xcd < 6) {
    if (slot < 44) {
      tensor = xcd >> 1; f = 3 + (xcd & 1); b = slot / 22; chunk = slot % 22;
    } else {
      int ss = slot - 44;
      tensor = xcd / 3; f = xcd % 3; b = ss >> 3; chunk = ss & 7;
    }
  } else if (xcd == 6) {
    if (slot >= 32) return;
    tensor = 2; f = slot >> 4; b = (slot >> 3) & 1; chunk = slot & 7;
  } else {
    if (slot >= 16) return;
    tensor = 2; f = 2; b = slot >> 3; chunk = slot & 7;
  }
  const int count = (f < 3) ? 57 : 171;
  const float* X  = (tensor == 0) ? Xq : (tensor == 1) ? Xk : Xv;
  const float* W  = (tensor == 0) ? Wq : (tensor == 1) ? Wk : Wv;
  const float* Bi = (tensor == 0) ? Bq : (tensor == 1) ? Bk : Bv;
  float* Y        = (tensor == 0) ? Yq : (tensor == 1) ? Yk : Yv;
  const int tid = threadIdx.x;
  {
    const int r = tid >> 7, c4 = (tid & 127) << 2;
    const int i = chunk * 8 + r;
    if (i < count) {
      const int t = trow(f, i);
      *(float4*)&xs[r][c4] = *(const float4*)(X + (size_t)(b * SS + t) * HH + c4);
    }
  }
  __syncthreads();
  const int wid = tid >> 6, lane = tid & 63;
  const int og = lane >> 3, kg = lane & 7;
  const float* Wf = W + (size_t)f * HH * HH;
  const int o0 = wid * 32, kbase = kg * 4;
  float acc[4][8];
#pragma unroll
  for (int bt = 0; bt < 4; ++bt)
#pragma unroll
    for (int r = 0; r < 8; ++r) acc[bt][r] = 0.f;
#pragma unroll
  for (int i = 0; i < 16; ++i) {
    float4 x4[8];
#pragma unroll
    for (int r = 0; r < 8; ++r) x4[r] = *(const float4*)&xs[r][kbase + i * 32];
#pragma unroll
    for (int bt = 0; bt < 4; ++bt) {
      const float4 w4 =
          *(const float4*)(Wf + (size_t)(o0 + bt * 8 + og) * HH + kbase + i * 32);
#pragma unroll
      for (int r = 0; r < 8; ++r) acc[bt][r] += dot4(w4, x4[r]);
    }
  }
#pragma unroll
  for (int bt = 0; bt < 4; ++bt)
#pragma unroll
    for (int r = 0; r < 8; ++r) acc[bt][r] = kg_reduce8(acc[bt][r]);
  if (kg == 0) {
#pragma unroll
    for (int bt = 0; bt < 4; ++bt) {
      const int o = o0 + bt * 8 + og;
      float bs = 0.f;
#pragma unroll
      for (int ff = 0; ff < 5; ++ff) bs += Bi[ff * HH + o];
#pragma unroll
      for (int r = 0; r < 8; ++r) {
        int i = chunk * 8 + r;
        if (i < count) {
          int t = trow(f, i);
          Y[(size_t)(b * SS + t) * HH + o] = acc[bt][r] + bs;
        }
      }
    }
  }
}

// FALLBACK proj (round 8). grid = 258, block = 1024.
__global__ __launch_bounds__(1024) void proj_f32_kernel(const float* __restrict__ Xin,
                                                        const float* __restrict__ Wo,
                                                        const float* __restrict__ bo,
                                                        float* __restrict__ out) {
  __shared__ float xs[8][HH];
  const int chunk = blockIdx.x >> 1;
  const int oc = blockIdx.x & 1;
  const int tid = threadIdx.x;
  const int NROW = BB * SS;
  {
    const int r = tid >> 7, c4 = (tid & 127) << 2;
    const int row = chunk * 8 + r;
    if (row < NROW)
      *(float4*)&xs[r][c4] = *(const float4*)(Xin + (size_t)row * HH + c4);
  }
  __syncthreads();
  const int wid = tid >> 6, lane = tid & 63;
  const int og = lane >> 3, kg = lane & 7;
  const int o0 = oc * 256 + wid * 16;
  const int kbase = kg * 4;
  float acc[2][8];
#pragma unroll
  for (int bt = 0; bt < 2; ++bt)
#pragma unroll
    for (int r = 0; r < 8; ++r) acc[bt][r] = 0.f;
#pragma unroll
  for (int i = 0; i < 16; ++i) {
    float4 x4[8];
#pragma unroll
    for (int r = 0; r < 8; ++r) x4[r] = *(const float4*)&xs[r][kbase + i * 32];
#pragma unroll
    for (int bt = 0; bt < 2; ++bt) {
      const float4 w4 =
          *(const float4*)(Wo + (size_t)(o0 + bt * 8 + og) * HH + kbase + i * 32);
#pragma unroll
      for (int r = 0; r < 8; ++r) acc[bt][r] += dot4(w4, x4[r]);
    }
  }
#pragma unroll
  for (int bt = 0; bt < 2; ++bt)
#pragma unroll
    for (int r = 0; r < 8; ++r) acc[bt][r] = kg_reduce8(acc[bt][r]);
  if (kg == 0) {
#pragma unroll
    for (int bt = 0; bt < 2; ++bt) {
      const int o = o0 + bt * 8 + og;
      const float bias = bo[o];
#pragma unroll
      for (int r = 0; r < 8; ++r) {
        int row = chunk * 8 + r;
        if (row < NROW) out[(size_t)row * HH + o] = acc[bt][r] + bias;
      }
    }
  }
}

// ---------------------------------------------------------------------------
// Fused: blocks 0..31 = partial V-sum; block 32 = graph layout detect.
__global__ __launch_bounds__(256) void vsum_detect_kernel(
    const float* __restrict__ V, float* __restrict__ part,
    const uint4* __restrict__ gv, int* __restrict__ flag) {
  if (blockIdx.x < 32) {
    int idx = (blockIdx.x & 3) * 256 + threadIdx.x;
    int p = blockIdx.x >> 2;
    int b = idx >> 9, o = idx & 511;
    float acc = 0.f;
    for (int t = p; t < SS; t += 8)
      acc += V[(size_t)(b * SS + t) * HH + o];
    part[p * 1024 + idx] = acc;
  } else {
    __shared__ int s;
    if (threadIdx.x == 0) s = 0;
    __syncthreads();
    unsigned int local = 0;
    for (int i = threadIdx.x; i < 2048; i += 256) {
      uint4 v = gv[i];
      local |= (v.x | v.y | v.z | v.w) & 0x0000ff00u;
    }
    if (local) atomicOr(&s, 1);
    __syncthreads();
    if (threadIdx.x == 0) *flag = s;
  }
}

// ---------------------------------------------------------------------------
// Fused attention: blocks [0,1020) sparse q>=3; blocks [1020,1836) dense scores.
__global__ __launch_bounds__(256) void attn_fused_kernel(
    const float* __restrict__ Q, const float* __restrict__ K, const float* __restrict__ V,
    const float* __restrict__ vsumPart, const void* __restrict__ graph,
    const int* __restrict__ flag,
    const float* __restrict__ EK, const float* __restrict__ EV, const float* __restrict__ EQ,
    float* __restrict__ X, float* __restrict__ sWS) {
  __shared__ float sQ[HH];
  __shared__ float sW[5 * NHH];
  __shared__ float sRed[4 * 64];
  __shared__ int sUni;

  const int tid = threadIdx.x, lane = tid & 63, wv = tid >> 6;
  const int isBool = *flag;

  if (blockIdx.x < 1020) {
    const int bid = blockIdx.x;
    const int b = bid / 510, q = 3 + bid % 510;
    const int row = b * SS + q;

    sQ[tid] = Q[(size_t)row * HH + tid];
    sQ[tid + 256] = Q[(size_t)row * HH + tid + 256];
    if (tid == 0) sUni = 0;
    __syncthreads();

    const int g = 3 + ((q - 3) >> 1) * 2;
    const size_t gbase = (size_t)b * SS * SS + (size_t)q * SS;
    const int h = lane >> 3, dg = lane & 7, d0 = dg * 8;

    for (int c = wv; c < 5; c += 4) {
      int k = (c < 3) ? c : g + (c - 3);
      bool m = graph_at(graph, isBool, gbase + k);
      const float* ekp = EK + (gbase + k) * DDIM + d0;
      const float* eqp = EQ + ((size_t)(b * SS + k) * SS + q) * DDIM + d0;
      const float* kp  = K + (size_t)(b * SS + k) * HH + h * 64 + d0;
      const float* qp  = &sQ[h * 64 + d0];
      float4 ek0 = *(const float4*)ekp, ek1 = *(const float4*)(ekp + 4);
      float4 eq0 = *(const float4*)eqp, eq1 = *(const float4*)(eqp + 4);
      float4 kk0 = *(const float4*)kp,  kk1 = *(const float4*)(kp + 4);
      float4 qq0 = *(const float4*)qp,  qq1 = *(const float4*)(qp + 4);
      float p = dot4(add4(qq0, eq0), add4(kk0, ek0)) + dot4(add4(qq1, eq1), add4(kk1, ek1));
      p += __shfl_xor(p, 1);
      p += __shfl_xor(p, 2);
      p += __shfl_xor(p, 4);
      if (dg == 0) sW[c * NHH + h] = m ? p * 0.125f : -1e30f;
    }
    __syncthreads();

    if (wv == 0) {
      int hh = lane >> 3, c = lane & 7;
      float s = (c < 5) ? sW[c * NHH + hh] : -1e30f;
      float mx = s;
#pragma unroll
      for (int off = 4; off; off >>= 1) mx = fmaxf(mx, __shfl_xor(mx, off));
      float e = (mx < -1e29f) ? 0.f : __expf(s - mx);
      float sum = e;
#pragma unroll
      for (int off = 4; off; off >>= 1) sum += __shfl_xor(sum, off);
      if (c < 5) sW[c * NHH + hh] = (mx < -1e29f) ? 0.f : e / sum;
      if (lane == 0 && mx < -1e29f) sUni = 1;
    }
    __syncthreads();

    if (sUni) {
      float acc = 0.f;
      for (int k = wv; k < SS; k += 4)
        acc += EV[(gbase + k) * DDIM + lane];
      sRed[wv * 64 + lane] = acc;
      __syncthreads();
      if (tid < 64) sRed[tid] = sRed[tid] + sRed[64 + tid] + sRed[128 + tid] + sRed[192 + tid];
      __syncthreads();
      const float c0 = 1.0f / 513.0f;
      for (int o = tid; o < HH; o += 256) {
        float vs = 0.f;
#pragma unroll
        for (int p = 0; p < 8; ++p) vs += vsumPart[p * 1024 + b * HH + o];
        X[(size_t)row * HH + o] = (vs + sRed[o & 63]) * c0;
      }
    } else {
#pragma unroll
      for (int rep = 0; rep < 2; ++rep) {
        int o = tid + rep * 256;
        int hh = o >> 6, d = o & 63;
        float acc = 0.f;
#pragma unroll
        for (int c = 0; c < 5; ++c) {
          int k = (c < 3) ? c : g + (c - 3);
          acc += sW[c * NHH + hh] *
                 (V[(size_t)(b * SS + k) * HH + o] + EV[(gbase + k) * DDIM + d]);
        }
        X[(size_t)row * HH + o] = acc;
      }
    }
  } else {
    const int bid = blockIdx.x - 1020;
    const int bqh = bid / 17, ks = bid % 17;
    const int b = bqh / 24, r = bqh % 24, q = r >> 3, hd = r & 7;
    const int kk = lane >> 3, dg = lane & 7, d0 = dg * 8;
    const int k = ks * 32 + wv * 8 + kk;
    const int kc = (k < SS) ? k : (SS - 1);
    const size_t gbase = (size_t)b * SS * SS + (size_t)q * SS;
    const bool m = (k < SS) && graph_at(graph, isBool, gbase + kc);

    const float* qp  = Q + (size_t)(b * SS + q) * HH + hd * 64 + d0;
    const float* ekp = EK + (gbase + kc) * DDIM + d0;
    const float* eqp = EQ + ((size_t)(b * SS + kc) * SS + q) * DDIM + d0;
    const float* kp  = K + (size_t)(b * SS + kc) * HH + hd * 64 + d0;
    float4 qq0 = *(const float4*)qp,  qq1 = *(const float4*)(qp + 4);
    float4 ek0 = *(const float4*)ekp, ek1 = *(const float4*)(ekp + 4);
    float4 eq0 = *(const float4*)eqp, eq1 = *(const float4*)(eqp + 4);
    float4 kk0 = *(const float4*)kp,  kk1 = *(const float4*)(kp + 4);
    float p = dot4(add4(qq0, eq0), add4(kk0, ek0)) + dot4(add4(qq1, eq1), add4(kk1, ek1));
    p += __shfl_xor(p, 1);
    p += __shfl_xor(p, 2);
    p += __shfl_xor(p, 4);
    if (dg == 0 && k < SS)
      sWS[(size_t)bqh * SS + k] = m ? p * 0.125f : -1e30f;
  }
}

// ---------------------------------------------------------------------------
// Dense finish: softmax + PV + combine, one block (1024 thr) per (b,q,h) = 48.
__global__ __launch_bounds__(1024) void dense_finish_kernel(
    const float* __restrict__ V, const float* __restrict__ EV,
    const float* __restrict__ sWS, float* __restrict__ X) {
  __shared__ float red[16];
  __shared__ float sP[SS];
  __shared__ float sOut[16][DDIM];

  const int bqh = blockIdx.x;
  const int b = bqh / 24, r2 = bqh % 24, q = r2 >> 3, hd = r2 & 7;
  const int tid = threadIdx.x, lane = tid & 63, wv = tid >> 6;
  const float* s = sWS + (size_t)bqh * SS;

  const float v = (tid < SS) ? s[tid] : -3e38f;
  float mx = v;
#pragma unroll
  for (int off = 32; off; off >>= 1) mx = fmaxf(mx, __shfl_xor(mx, off));
  if (lane == 0) red[wv] = mx;
  __syncthreads();
  float mxAll = -3e38f;
#pragma unroll
  for (int j = 0; j < 16; ++j) mxAll = fmaxf(mxAll, red[j]);

  float p;
  if (mxAll < -1e29f) {
    p = 1.0f / 513.0f;
  } else {
    float e = (tid < SS) ? __expf(v - mxAll) : 0.f;
    float sm = e;
#pragma unroll
    for (int off = 32; off; off >>= 1) sm += __shfl_xor(sm, off);
    __syncthreads();
    if (lane == 0) red[wv] = sm;
    __syncthreads();
    float tot = 0.f;
#pragma unroll
    for (int j = 0; j < 16; ++j) tot += red[j];
    p = e / tot;
  }
  if (tid < SS) sP[tid] = p;
  __syncthreads();

  const int d = tid & 63, kc = tid >> 6;
  const size_t evb = ((size_t)(b * SS + q) * SS) * DDIM;
  float acc = 0.f;
  for (int k = kc; k < SS; k += 16)
    acc += sP[k] * (V[(size_t)(b * SS + k) * HH + hd * 64 + d] +
                    EV[evb + (size_t)k * DDIM + d]);
  sOut[kc][d] = acc;
  __syncthreads();
  if (tid < 64) {
    float t = 0.f;
#pragma unroll
    for (int j = 0; j < 16; ++j) t += sOut[j][tid];
    X[(size_t)(b * SS + q) * HH + hd * 64 + tid] = t;
  }
}

// ---------------------------------------------------------------------------
extern "C" void kernel_launch(void* const* d_in, const int* in_sizes, int n_in,
                              void* d_out, int out_size, void* d_ws, size_t ws_size,
                              hipStream_t stream) {
  (void)in_sizes; (void)n_in; (void)out_size;
  const float* query = (const float*)d_in[0];
  const float* key   = (const float*)d_in[1];
  const float* value = (const float*)d_in[2];
  const void*  graph = d_in[3];
  const float* EK = (const float*)d_in[4];
  const float* EV = (const float*)d_in[5];
  const float* EQ = (const float*)d_in[6];
  const float* Wq = (const float*)d_in[7];
  const float* bq = (const float*)d_in[8];
  const float* Wk = (const float*)d_in[9];
  const float* bk = (const float*)d_in[10];
  const float* Wv = (const float*)d_in[11];
  const float* bv = (const float*)d_in[12];
  const float* Wo = (const float*)d_in[13];
  const float* bo = (const float*)d_in[14];
  float* out = (float*)d_out;

  char* ws = (char*)d_ws;
  int*   flag = (int*)ws;
  float* part = (float*)(ws + OFF_PART);
  float* Qp = (float*)(ws + OFF_QP);
  float* Kp = (float*)(ws + OFF_KP);
  float* Vp = (float*)(ws + OFF_VP);
  float* Xp = (float*)(ws + OFF_XPP);
  float* sWS = (float*)(ws + OFF_SWS);
  ushort_t* WBF  = (ushort_t*)(ws + OFF_WBF);
  ushort_t* XBFP = (ushort_t*)(ws + OFF_XBFP);
  ushort_t* XBFO = (ushort_t*)(ws + OFF_XBFO);

  const bool useMfma = ws_size >= WS_NEED;

  if (useMfma) {
    conv_w_kernel<<<2048, 256, 0, stream>>>(Wq, Wk, Wv, Wo, WBF);
    conv_x_kernel<<<816, 256, 0, stream>>>(query, key, value, XBFP);
    gemm_prep_kernel<<<208, 256, 0, stream>>>(WBF, XBFP, bq, bk, bv, Qp, Kp, Vp);
  } else {
    prep_f32_kernel<<<480, 1024, 0, stream>>>(query, key, value, Wq, Wk, Wv,
                                              bq, bk, bv, Qp, Kp, Vp);
  }
  vsum_detect_kernel<<<33, 256, 0, stream>>>(Vp, part, (const uint4*)graph, flag);
  attn_fused_kernel<<<1020 + 48 * 17, 256, 0, stream>>>(Qp, Kp, Vp, part, graph, flag,
                                                        EK, EV, EQ, Xp, sWS);
  dense_finish_kernel<<<48, 1024, 0, stream>>>(Vp, EV, sWS, Xp);
  if (useMfma) {
    conv_xo_kernel<<<264, 256, 0, stream>>>(Xp, XBFO);
    gemm_proj_kernel<<<66, 256, 0, stream>>>(WBF, XBFO, bo, out);
  } else {
    proj_f32_kernel<<<258, 1024, 0, stream>>>(Xp, Wo, bo, out);
  }
}